// Round 17
// baseline (93.683 us; speedup 1.0000x reference)
//
#include <hip/hip_runtime.h>
#include <hip/hip_cooperative_groups.h>

namespace cg = cooperative_groups;

typedef unsigned long long u64;

#define NB 64
#define NQ 900
#define NCLS 81     // C+1
#define NLAB 81
#define NVERB 117
#define NBQ (NB*NQ)
#define NWORD 15    // ceil(900/64)
#define NBLK 225    // grid: 225 blocks x 1024 threads (1 block/CU, co-resident)
#define NWAVE (NBLK*16)

// ---- wave64 max-reduce on the VALU pipe (DPP), result uniform in all lanes.
__device__ __forceinline__ float wave_max_dpp(float m) {
    unsigned mu;
    mu = __float_as_uint(m);
    m = fmaxf(m, __uint_as_float(__builtin_amdgcn_update_dpp(mu, mu, 0x111, 0xF, 0xF, false)));
    mu = __float_as_uint(m);
    m = fmaxf(m, __uint_as_float(__builtin_amdgcn_update_dpp(mu, mu, 0x112, 0xF, 0xF, false)));
    mu = __float_as_uint(m);
    m = fmaxf(m, __uint_as_float(__builtin_amdgcn_update_dpp(mu, mu, 0x114, 0xF, 0xF, false)));
    mu = __float_as_uint(m);
    m = fmaxf(m, __uint_as_float(__builtin_amdgcn_update_dpp(mu, mu, 0x118, 0xF, 0xF, false)));
    mu = __float_as_uint(m);
    m = fmaxf(m, __uint_as_float(__builtin_amdgcn_update_dpp(mu, mu, 0x142, 0xF, 0xF, false)));
    mu = __float_as_uint(m);
    m = fmaxf(m, __uint_as_float(__builtin_amdgcn_update_dpp(mu, mu, 0x143, 0xF, 0xF, false)));
    return __uint_as_float(__builtin_amdgcn_readlane(__float_as_uint(m), 63));
}

__device__ __forceinline__ float bc(float x, int r) {
    return __uint_as_float(__builtin_amdgcn_readlane(__float_as_uint(x), r));
}

__device__ __forceinline__ bool iou_pred(
    const float4& sj, const float4& oj, float saj, float oaj,
    float six, float siy, float siz, float siw,
    float oix, float oiy, float oiz, float oiw, float sai, float oai)
{
    float xx1 = fmaxf(six, sj.x), yy1 = fmaxf(siy, sj.y);
    float xx2 = fminf(siz, sj.z), yy2 = fminf(siw, sj.w);
    float w = fmaxf(0.0f, xx2 - xx1 + 1.0f);
    float h = fmaxf(0.0f, yy2 - yy1 + 1.0f);
    float iS = w * h, uS = sai + saj - iS;
    xx1 = fmaxf(oix, oj.x); yy1 = fmaxf(oiy, oj.y);
    xx2 = fminf(oiz, oj.z); yy2 = fminf(oiw, oj.w);
    w = fmaxf(0.0f, xx2 - xx1 + 1.0f);
    h = fmaxf(0.0f, yy2 - yy1 + 1.0f);
    float iO = w * h, uO = oai + oaj - iO;
    // iouS * sqrt(iouO) > 0.7  <=>  iS^2*iO > 0.49*uS^2*uO  (all nonneg)
    return iS * iS * iO > 0.49f * uS * uS * uO;
}

// ===== Fused single-dispatch kernel: phase1 = kA (R16), grid-sync,
// ===== phase2 = per-(batch,label) NMS with in-wave sort (R16 kE).
__global__ __launch_bounds__(1024) void kF(
    const float* __restrict__ obj_logits, const float* __restrict__ verb_logits,
    const float* __restrict__ sub_boxes, const float* __restrict__ obj_boxes,
    const int* __restrict__ target_sizes, const float* __restrict__ cmat,
    float* __restrict__ out_hoi, float* __restrict__ out_lab,
    float* __restrict__ out_sb, float* __restrict__ out_ob,
    float* __restrict__ ws_max, int* __restrict__ ws_lab,
    float* __restrict__ sar, float* __restrict__ oar,
    float* __restrict__ out_keep)
{
    // 115200 B, phase-unioned: phase1 cmT (37440 B) / phase2 16x7200 B wave arrays
    __shared__ float smemf[28800];
    __shared__ u64 keptm[16][NWORD];
    int t = threadIdx.x, lane = t & 63, wv = t >> 6;

    // ================= PHASE 1: scores / labels / boxes =================
    {
        float* cmT = smemf;                     // cmT[c*117+v] = cmat[v*80+c]
        for (int i = t; i < 80 * 117; i += 1024) {
            int v = i / 80, c = i - v * 80;
            cmT[c * 117 + v] = cmat[i];
        }
        __syncthreads();

        #pragma unroll
        for (int it = 0; it < 4; ++it) {
            int w0 = blockIdx.x * 256 + wv * 16 + it * 4;
            int b = w0 / NQ;

            const float* ol = obj_logits  + (size_t)w0 * NCLS;
            const float* vl = verb_logits + (size_t)w0 * NVERB;
            float A[4], Bv[4], va[4], vb[4];
            #pragma unroll
            for (int r = 0; r < 4; ++r) {
                A[r]  = ol[r * NCLS + lane];
                Bv[r] = (lane < NCLS - 64) ? ol[r * NCLS + 64 + lane] : -3.4e38f;
                va[r] = vl[r * NVERB + lane];
                vb[r] = (lane < NVERB - 64) ? vl[r * NVERB + 64 + lane] : 0.0f;
            }

            float OS[4]; int MI[4];
            #pragma unroll
            for (int r = 0; r < 4; ++r) {
                float m = wave_max_dpp(fmaxf(A[r], Bv[r]));
                u64 balA = __ballot((int)(A[r] == m));
                u64 balB = __ballot((int)(lane < NCLS - 64 && Bv[r] == m));
                MI[r] = balA ? (__ffsll(balA) - 1) : (63 + __ffsll(balB));
                OS[r] = __fdividef(1.0f, 1.0f + __expf(-m));
            }

            float MX[4];
            #pragma unroll
            for (int r = 0; r < 4; ++r) {
                float ka = (MI[r] < 80) ? cmT[MI[r] * 117 + lane] : 1.0f;
                float kb = 0.0f;
                if (lane < NVERB - 64)
                    kb = (MI[r] < 80) ? cmT[MI[r] * 117 + 64 + lane] : 1.0f;
                float* oh = out_hoi + (size_t)(w0 + r) * NVERB;
                float ha = __fdividef(OS[r] * ka, 1.0f + __expf(-va[r]));
                float hb = -1.0f;
                if (lane < NVERB - 64) {
                    hb = __fdividef(OS[r] * kb, 1.0f + __expf(-vb[r]));
                    __builtin_nontemporal_store(hb, &oh[64 + lane]);
                }
                __builtin_nontemporal_store(ha, &oh[lane]);
                MX[r] = wave_max_dpp(fmaxf(ha, hb));
            }

            if (lane < 4) {
                int   mi = (lane == 0) ? MI[0] : (lane == 1) ? MI[1] : (lane == 2) ? MI[2] : MI[3];
                float mx = (lane == 0) ? MX[0] : (lane == 1) ? MX[1] : (lane == 2) ? MX[2] : MX[3];
                out_lab[w0 + lane] = (float)mi;
                ws_lab[w0 + lane]  = mi;
                ws_max[w0 + lane]  = mx;
            }

            if (lane < 8) {
                int row = w0 + (lane >> 1);
                const float* bx = ((lane & 1) == 0 ? sub_boxes : obj_boxes) + (size_t)row * 4;
                float* o = ((lane & 1) == 0 ? out_sb : out_ob) + (size_t)row * 4;
                float ih = (float)target_sizes[b * 2 + 0];
                float iw = (float)target_sizes[b * 2 + 1];
                float4 v = *(const float4*)bx;
                float x1 = (v.x - 0.5f * v.z) * iw, y1 = (v.y - 0.5f * v.w) * ih;
                float x2 = (v.x + 0.5f * v.z) * iw, y2 = (v.y + 0.5f * v.w) * ih;
                *(float4*)o = make_float4(x1, y1, x2, y2);
                float ar = (x2 - x1 + 1.0f) * (y2 - y1 + 1.0f);
                ((lane & 1) == 0 ? sar : oar)[row] = ar;
            }
        }
    }

    // ============== grid-wide sync (device-scope fence included) ==============
    cg::this_grid().sync();

    // ================= PHASE 2: per-(batch,label) greedy NMS =================
    {
        char* wbase = (char*)smemf + wv * 7200;
        float*          msc = (float*)wbase;                    // member scores
        unsigned short* mq  = (unsigned short*)(wbase + 3600);  // member orig q
        unsigned short* mem = (unsigned short*)(wbase + 5400);  // sorted orig q
        const float4* sb4 = (const float4*)out_sb;
        const float4* ob4 = (const float4*)out_ob;

        int gw = blockIdx.x * 16 + wv;
        for (int idx = gw; idx < NB * NLAB; idx += NWAVE) {
            int b = idx / NLAB, l = idx - b * NLAB;
            int base = b * NQ;

            // ---- collect members of label l in q-ascending order ----
            int g = 0;
            for (int k0_ = 0; k0_ < NQ; k0_ += 64) {
                int k = k0_ + lane;
                int   lb = (k < NQ) ? ws_lab[base + k] : -1;
                float sc = (k < NQ) ? ws_max[base + k] : 0.0f;
                u64 bal = __ballot((int)(lb == l));
                if (lb == l) {
                    int pos = g + __popcll(bal & (((u64)1 << lane) - 1));
                    msc[pos] = sc;
                    mq[pos]  = (unsigned short)k;
                }
                g += __popcll(bal);
            }

            // ---- in-wave stable rank sort by (score desc, q asc) ----
            int nch = (g + 63) >> 6;
            for (int cm = 0; cm < nch; ++cm) {
                int m = cm * 64 + lane;
                bool vld = m < g;
                float s = vld ? msc[m] : 0.0f;
                int   q = vld ? (int)mq[m] : 0;
                int rank = 0;
                for (int j = 0; j < g; ++j) {
                    float sj = msc[j];
                    int   qj = mq[j];
                    rank += (sj > s) || (sj == s && qj < q);
                }
                if (vld) mem[rank] = (unsigned short)q;
            }

            // ---- chunked greedy NMS over sorted members ----
            for (int c = 0; c < nch; ++c) {
                int rows = min(64, g - c * 64);
                bool vld = lane < rows;
                int oq = vld ? (int)mem[c * 64 + lane] : 0;
                float4 sj = sb4[base + oq];
                float4 oj = ob4[base + oq];
                float saj = sar[base + oq], oaj = oar[base + oq];

                u64 pre = 0ull;
                for (int e = 0; e < c; ++e) {
                    int oqE = (int)mem[e * 64 + lane];
                    float4 sE = sb4[base + oqE];
                    float4 oE = ob4[base + oqE];
                    float saE = sar[base + oqE], oaE = oar[base + oqE];
                    u64 ke = keptm[wv][e];
                    for (int r = 0; r < 64; ++r) {
                        if ((ke >> r) & 1ull) {
                            bool p = vld && iou_pred(sj, oj, saj, oaj,
                                bc(sE.x, r), bc(sE.y, r), bc(sE.z, r), bc(sE.w, r),
                                bc(oE.x, r), bc(oE.y, r), bc(oE.z, r), bc(oE.w, r),
                                bc(saE, r), bc(oaE, r));
                            pre |= __ballot((int)p);
                        }
                    }
                }

                u64 myword = 0ull;
                for (int r = 0; r < rows; ++r) {
                    bool p = vld && (lane > r) && iou_pred(sj, oj, saj, oaj,
                        bc(sj.x, r), bc(sj.y, r), bc(sj.z, r), bc(sj.w, r),
                        bc(oj.x, r), bc(oj.y, r), bc(oj.z, r), bc(oj.w, r),
                        bc(saj, r), bc(oaj, r));
                    u64 bal = __ballot((int)p);
                    if (lane == r) myword = bal;
                }

                unsigned ilo = (unsigned)myword, ihi = (unsigned)(myword >> 32);
                u64 supp = pre;
                for (int r = 0; r < rows; ++r) {
                    u64 rowr = ((u64)__builtin_amdgcn_readlane(ihi, r) << 32)
                             |  (u64)__builtin_amdgcn_readlane(ilo, r);
                    supp |= ((supp >> r) & 1ull) ? 0ull : rowr;
                }
                u64 keep = ~supp;
                if (lane == 0)
                    keptm[wv][c] = keep & ((rows == 64) ? ~0ull : (((u64)1 << rows) - 1));
                if (vld)
                    out_keep[base + oq] = ((keep >> lane) & 1ull) ? 1.0f : 0.0f;
            }
        }
    }
}

extern "C" void kernel_launch(void* const* d_in, const int* in_sizes, int n_in,
                              void* d_out, int out_size, void* d_ws, size_t ws_size,
                              hipStream_t stream)
{
    const float* obj_logits   = (const float*)d_in[0];
    const float* verb_logits  = (const float*)d_in[1];
    const float* sub_boxes    = (const float*)d_in[2];
    const float* obj_boxes    = (const float*)d_in[3];
    const int*   target_sizes = (const int*)d_in[4];
    const float* cmat         = (const float*)d_in[5];

    float* out      = (float*)d_out;
    float* out_hoi  = out;
    float* out_lab  = out_hoi + (size_t)NBQ * NVERB;
    float* out_sb   = out_lab + NBQ;
    float* out_ob   = out_sb + (size_t)NBQ * 4;
    float* out_keep = out_ob + (size_t)NBQ * 4;

    char* w = (char*)d_ws;
    float* ws_max = (float*)w;   w += (size_t)NBQ * 4;
    float* sar    = (float*)w;   w += (size_t)NBQ * 4;
    float* oar    = (float*)w;   w += (size_t)NBQ * 4;
    int*   ws_lab = (int*)w;     w += (size_t)NBQ * 4;

    void* args[] = {
        (void*)&obj_logits, (void*)&verb_logits, (void*)&sub_boxes,
        (void*)&obj_boxes, (void*)&target_sizes, (void*)&cmat,
        (void*)&out_hoi, (void*)&out_lab, (void*)&out_sb, (void*)&out_ob,
        (void*)&ws_max, (void*)&ws_lab, (void*)&sar, (void*)&oar,
        (void*)&out_keep
    };
    hipLaunchCooperativeKernel((void*)kF, dim3(NBLK), dim3(1024), args, 0, stream);
}

// Round 18
// 44.039 us; speedup vs baseline: 2.1273x; 2.1273x over previous
//
#include <hip/hip_runtime.h>

typedef unsigned long long u64;

#define NB 64
#define NQ 900
#define NCLS 81     // C+1
#define NLAB 81
#define NVERB 117
#define NBQ (NB*NQ)
#define NWORD 15    // ceil(900/64)

// ---- wave64 max-reduce on the VALU pipe (DPP), result uniform in all lanes.
__device__ __forceinline__ float wave_max_dpp(float m) {
    unsigned mu;
    mu = __float_as_uint(m);
    m = fmaxf(m, __uint_as_float(__builtin_amdgcn_update_dpp(mu, mu, 0x111, 0xF, 0xF, false)));
    mu = __float_as_uint(m);
    m = fmaxf(m, __uint_as_float(__builtin_amdgcn_update_dpp(mu, mu, 0x112, 0xF, 0xF, false)));
    mu = __float_as_uint(m);
    m = fmaxf(m, __uint_as_float(__builtin_amdgcn_update_dpp(mu, mu, 0x114, 0xF, 0xF, false)));
    mu = __float_as_uint(m);
    m = fmaxf(m, __uint_as_float(__builtin_amdgcn_update_dpp(mu, mu, 0x118, 0xF, 0xF, false)));
    mu = __float_as_uint(m);
    m = fmaxf(m, __uint_as_float(__builtin_amdgcn_update_dpp(mu, mu, 0x142, 0xF, 0xF, false)));
    mu = __float_as_uint(m);
    m = fmaxf(m, __uint_as_float(__builtin_amdgcn_update_dpp(mu, mu, 0x143, 0xF, 0xF, false)));
    return __uint_as_float(__builtin_amdgcn_readlane(__float_as_uint(m), 63));
}

// ===== K1: fused mask-transpose + scores/labels/boxes (R16, unchanged) =====
__global__ __launch_bounds__(1024) void kA(
    const float* __restrict__ obj_logits, const float* __restrict__ verb_logits,
    const float* __restrict__ sub_boxes, const float* __restrict__ obj_boxes,
    const int* __restrict__ target_sizes, const float* __restrict__ cmat,
    float* __restrict__ out_hoi, float* __restrict__ out_lab,
    float* __restrict__ out_sb, float* __restrict__ out_ob,
    float* __restrict__ ws_max, int* __restrict__ ws_lab,
    float* __restrict__ sar, float* __restrict__ oar)
{
    __shared__ float cmT[80 * 117];          // cmT[c*117+v] = cmat[v*80+c]
    int t = threadIdx.x, lane = t & 63, wv = t >> 6;
    for (int i = t; i < 80 * 117; i += 1024) {
        int v = i / 80, c = i - v * 80;
        cmT[c * 117 + v] = cmat[i];
    }
    __syncthreads();

    #pragma unroll
    for (int it = 0; it < 4; ++it) {
        int w0 = blockIdx.x * 256 + wv * 16 + it * 4;
        int b = w0 / NQ;

        const float* ol = obj_logits  + (size_t)w0 * NCLS;
        const float* vl = verb_logits + (size_t)w0 * NVERB;
        float A[4], Bv[4], va[4], vb[4];
        #pragma unroll
        for (int r = 0; r < 4; ++r) {
            A[r]  = ol[r * NCLS + lane];
            Bv[r] = (lane < NCLS - 64) ? ol[r * NCLS + 64 + lane] : -3.4e38f;
            va[r] = vl[r * NVERB + lane];
            vb[r] = (lane < NVERB - 64) ? vl[r * NVERB + 64 + lane] : 0.0f;
        }

        float OS[4]; int MI[4];
        #pragma unroll
        for (int r = 0; r < 4; ++r) {
            float m = wave_max_dpp(fmaxf(A[r], Bv[r]));
            u64 balA = __ballot((int)(A[r] == m));
            u64 balB = __ballot((int)(lane < NCLS - 64 && Bv[r] == m));
            MI[r] = balA ? (__ffsll(balA) - 1) : (63 + __ffsll(balB));
            OS[r] = __fdividef(1.0f, 1.0f + __expf(-m));
        }

        float MX[4];
        #pragma unroll
        for (int r = 0; r < 4; ++r) {
            float ka = (MI[r] < 80) ? cmT[MI[r] * 117 + lane] : 1.0f;
            float kb = 0.0f;
            if (lane < NVERB - 64)
                kb = (MI[r] < 80) ? cmT[MI[r] * 117 + 64 + lane] : 1.0f;
            float* oh = out_hoi + (size_t)(w0 + r) * NVERB;
            float ha = __fdividef(OS[r] * ka, 1.0f + __expf(-va[r]));
            float hb = -1.0f;
            if (lane < NVERB - 64) {
                hb = __fdividef(OS[r] * kb, 1.0f + __expf(-vb[r]));
                __builtin_nontemporal_store(hb, &oh[64 + lane]);
            }
            __builtin_nontemporal_store(ha, &oh[lane]);
            MX[r] = wave_max_dpp(fmaxf(ha, hb));
        }

        if (lane < 4) {
            int   mi = (lane == 0) ? MI[0] : (lane == 1) ? MI[1] : (lane == 2) ? MI[2] : MI[3];
            float mx = (lane == 0) ? MX[0] : (lane == 1) ? MX[1] : (lane == 2) ? MX[2] : MX[3];
            out_lab[w0 + lane] = (float)mi;
            ws_lab[w0 + lane]  = mi;
            ws_max[w0 + lane]  = mx;
        }

        if (lane < 8) {
            int row = w0 + (lane >> 1);
            const float* bx = ((lane & 1) == 0 ? sub_boxes : obj_boxes) + (size_t)row * 4;
            float* o = ((lane & 1) == 0 ? out_sb : out_ob) + (size_t)row * 4;
            float ih = (float)target_sizes[b * 2 + 0];
            float iw = (float)target_sizes[b * 2 + 1];
            float4 v = *(const float4*)bx;
            float x1 = (v.x - 0.5f * v.z) * iw, y1 = (v.y - 0.5f * v.w) * ih;
            float x2 = (v.x + 0.5f * v.z) * iw, y2 = (v.y + 0.5f * v.w) * ih;
            *(float4*)o = make_float4(x1, y1, x2, y2);
            float ar = (x2 - x1 + 1.0f) * (y2 - y1 + 1.0f);
            ((lane & 1) == 0 ? sar : oar)[row] = ar;
        }
    }
}

// ===== K2: per-(batch,label) NMS; register fast path for g <= 64 ===========
__device__ __forceinline__ float bc(float x, int r) {
    return __uint_as_float(__builtin_amdgcn_readlane(__float_as_uint(x), r));
}

__device__ __forceinline__ bool iou_pred(
    const float4& sj, const float4& oj, float saj, float oaj,
    float six, float siy, float siz, float siw,
    float oix, float oiy, float oiz, float oiw, float sai, float oai)
{
    float xx1 = fmaxf(six, sj.x), yy1 = fmaxf(siy, sj.y);
    float xx2 = fminf(siz, sj.z), yy2 = fminf(siw, sj.w);
    float w = fmaxf(0.0f, xx2 - xx1 + 1.0f);
    float h = fmaxf(0.0f, yy2 - yy1 + 1.0f);
    float iS = w * h, uS = sai + saj - iS;
    xx1 = fmaxf(oix, oj.x); yy1 = fmaxf(oiy, oj.y);
    xx2 = fminf(oiz, oj.z); yy2 = fminf(oiw, oj.w);
    w = fmaxf(0.0f, xx2 - xx1 + 1.0f);
    h = fmaxf(0.0f, yy2 - yy1 + 1.0f);
    float iO = w * h, uO = oai + oaj - iO;
    // iouS * sqrt(iouO) > 0.7  <=>  iS^2*iO > 0.49*uS^2*uO  (all nonneg)
    return iS * iS * iO > 0.49f * uS * uS * uO;
}

__global__ __launch_bounds__(256) void kE(
    const float* __restrict__ ws_max, const int* __restrict__ ws_lab,
    const float* __restrict__ out_sb, const float* __restrict__ out_ob,
    const float* __restrict__ sar, const float* __restrict__ oar,
    float* __restrict__ out_keep)
{
    __shared__ float           msc[4][NQ];
    __shared__ unsigned short  mq[4][NQ];
    __shared__ unsigned short  mem[4][NQ];
    __shared__ u64 keptm[4][NWORD];
    const float4* sb4 = (const float4*)out_sb;
    const float4* ob4 = (const float4*)out_ob;
    int b = blockIdx.y, base = b * NQ;
    int lane = threadIdx.x & 63, wv = threadIdx.x >> 6;
    int l = blockIdx.x * 4 + wv;
    if (l >= NLAB) return;
    u64 lmask = ((u64)1 << lane) - 1;

    // ---- prefetch ALL collect loads (15 independent rounds), then ballot ----
    int   lbv[NWORD]; float scv[NWORD];
    #pragma unroll
    for (int c = 0; c < NWORD; ++c) {
        int k = c * 64 + lane;
        bool in = k < NQ;
        lbv[c] = in ? ws_lab[base + k] : -1;
        scv[c] = in ? ws_max[base + k] : 0.0f;
    }
    int g = 0;
    #pragma unroll
    for (int c = 0; c < NWORD; ++c) {
        bool isl = lbv[c] == l;
        u64 bal = __ballot((int)isl);
        if (isl) {
            int pos = g + __popcll(bal & lmask);
            msc[wv][pos] = scv[c];
            mq[wv][pos]  = (unsigned short)(c * 64 + lane);
        }
        g += __popcll(bal);
    }
    if (g == 0) return;

    if (g <= 64) {
        // ================= register fast path (no LDS on critical path) ====
        bool vld = lane < g;
        float s = vld ? msc[wv][lane] : 0.0f;
        int   q = vld ? (int)mq[wv][lane] : 0;
        // rank by (score desc, q asc) via readlane broadcasts (VALU only)
        int rank = 0;
        for (int j = 0; j < g; ++j) {
            float sj = bc(s, j);
            int   qj = __builtin_amdgcn_readlane(q, j);
            rank += (sj > s) || (sj == s && qj < q);
        }
        // scatter q to lane 'rank' (invalid lanes push to dead lane 63)
        int oq = __builtin_amdgcn_ds_permute((vld ? rank : 63) << 2, q);
        if (!vld) oq = 0;

        float4 sj4 = sb4[base + oq];
        float4 oj4 = ob4[base + oq];
        float saj = sar[base + oq], oaj = oar[base + oq];

        u64 myword = 0ull;
        for (int r = 0; r < g; ++r) {
            bool p = vld && (lane > r) && iou_pred(sj4, oj4, saj, oaj,
                bc(sj4.x, r), bc(sj4.y, r), bc(sj4.z, r), bc(sj4.w, r),
                bc(oj4.x, r), bc(oj4.y, r), bc(oj4.z, r), bc(oj4.w, r),
                bc(saj, r), bc(oaj, r));
            u64 bal = __ballot((int)p);
            if (lane == r) myword = bal;
        }
        unsigned ilo = (unsigned)myword, ihi = (unsigned)(myword >> 32);
        u64 supp = 0ull;
        for (int r = 0; r < g; ++r) {
            u64 rowr = ((u64)__builtin_amdgcn_readlane(ihi, r) << 32)
                     |  (u64)__builtin_amdgcn_readlane(ilo, r);
            supp |= ((supp >> r) & 1ull) ? 0ull : rowr;
        }
        u64 keep = ~supp;
        if (vld)
            out_keep[base + oq] = ((keep >> lane) & 1ull) ? 1.0f : 0.0f;
        return;
    }

    // ================= general path g > 64 (R16 code, unchanged) ===========
    int nch = (g + 63) >> 6;
    for (int cm = 0; cm < nch; ++cm) {
        int m = cm * 64 + lane;
        bool vld = m < g;
        float s = vld ? msc[wv][m] : 0.0f;
        int   q = vld ? (int)mq[wv][m] : 0;
        int rank = 0;
        for (int j = 0; j < g; ++j) {
            float sj = msc[wv][j];
            int   qj = mq[wv][j];
            rank += (sj > s) || (sj == s && qj < q);
        }
        if (vld) mem[wv][rank] = (unsigned short)q;
    }

    for (int c = 0; c < nch; ++c) {
        int rows = min(64, g - c * 64);
        bool vld = lane < rows;
        int oq = vld ? (int)mem[wv][c * 64 + lane] : 0;
        float4 sj = sb4[base + oq];
        float4 oj = ob4[base + oq];
        float saj = sar[base + oq], oaj = oar[base + oq];

        u64 pre = 0ull;
        for (int e = 0; e < c; ++e) {
            int oqE = (int)mem[wv][e * 64 + lane];
            float4 sE = sb4[base + oqE];
            float4 oE = ob4[base + oqE];
            float saE = sar[base + oqE], oaE = oar[base + oqE];
            u64 ke = keptm[wv][e];
            for (int r = 0; r < 64; ++r) {
                if ((ke >> r) & 1ull) {
                    bool p = vld && iou_pred(sj, oj, saj, oaj,
                        bc(sE.x, r), bc(sE.y, r), bc(sE.z, r), bc(sE.w, r),
                        bc(oE.x, r), bc(oE.y, r), bc(oE.z, r), bc(oE.w, r),
                        bc(saE, r), bc(oaE, r));
                    pre |= __ballot((int)p);
                }
            }
        }

        u64 myword = 0ull;
        for (int r = 0; r < rows; ++r) {
            bool p = vld && (lane > r) && iou_pred(sj, oj, saj, oaj,
                bc(sj.x, r), bc(sj.y, r), bc(sj.z, r), bc(sj.w, r),
                bc(oj.x, r), bc(oj.y, r), bc(oj.z, r), bc(oj.w, r),
                bc(saj, r), bc(oaj, r));
            u64 bal = __ballot((int)p);
            if (lane == r) myword = bal;
        }

        unsigned ilo = (unsigned)myword, ihi = (unsigned)(myword >> 32);
        u64 supp = pre;
        for (int r = 0; r < rows; ++r) {
            u64 rowr = ((u64)__builtin_amdgcn_readlane(ihi, r) << 32)
                     |  (u64)__builtin_amdgcn_readlane(ilo, r);
            supp |= ((supp >> r) & 1ull) ? 0ull : rowr;
        }
        u64 keep = ~supp;
        if (lane == 0)
            keptm[wv][c] = keep & ((rows == 64) ? ~0ull : (((u64)1 << rows) - 1));
        if (vld)
            out_keep[base + oq] = ((keep >> lane) & 1ull) ? 1.0f : 0.0f;
    }
}

extern "C" void kernel_launch(void* const* d_in, const int* in_sizes, int n_in,
                              void* d_out, int out_size, void* d_ws, size_t ws_size,
                              hipStream_t stream)
{
    const float* obj_logits   = (const float*)d_in[0];
    const float* verb_logits  = (const float*)d_in[1];
    const float* sub_boxes    = (const float*)d_in[2];
    const float* obj_boxes    = (const float*)d_in[3];
    const int*   target_sizes = (const int*)d_in[4];
    const float* cmat         = (const float*)d_in[5];

    float* out      = (float*)d_out;
    float* out_hoi  = out;
    float* out_lab  = out_hoi + (size_t)NBQ * NVERB;
    float* out_sb   = out_lab + NBQ;
    float* out_ob   = out_sb + (size_t)NBQ * 4;
    float* out_keep = out_ob + (size_t)NBQ * 4;

    char* w = (char*)d_ws;
    float* ws_max = (float*)w;   w += (size_t)NBQ * 4;
    float* sar    = (float*)w;   w += (size_t)NBQ * 4;
    float* oar    = (float*)w;   w += (size_t)NBQ * 4;
    int*   ws_lab = (int*)w;     w += (size_t)NBQ * 4;

    kA<<<NBQ / 256, 1024, 0, stream>>>(obj_logits, verb_logits,
                                       sub_boxes, obj_boxes, target_sizes, cmat,
                                       out_hoi, out_lab, out_sb, out_ob,
                                       ws_max, ws_lab, sar, oar);
    kE<<<dim3((NLAB + 3) / 4, NB), 256, 0, stream>>>(ws_max, ws_lab,
                                                     out_sb, out_ob, sar, oar,
                                                     out_keep);
}